// Round 12
// baseline (392.851 us; speedup 1.0000x reference)
//
#include <hip/hip_runtime.h>
#include <math.h>

#define NB 8192
#define T 65
#define Q 20
#define D 100
#define D4 25        // D/4
#define SP4 5        // sS row pitch in float4 (= Q floats exactly)
#define NBPB 8       // batches per block -> grid 1024 = exactly 4 blocks/CU

__global__ __launch_bounds__(256, 4) void attn_fused_kernel(
    const float* __restrict__ Hg,   // [B,T,D]
    const float* __restrict__ Ug,   // [B,Q,D]
    const float* __restrict__ Ws1,  // [T,D] (tiled single row)
    const float* __restrict__ Ws2,  // [Q,D]
    const float* __restrict__ Ws3,  // [T,D]
    float* __restrict__ Gg)         // [B,T,4D]
{
    // 26000 + 8400 + 5200 + 800 + 160 + 260 = 40820 B -> 4 blocks/CU
    __shared__ float4 sH4[T*D4];          // 26000 B (single buffer; refilled in P7)
    __shared__ float4 sU3e4[(Q+1)*D4];    //  8400 B: rows 0..19 = U*w3, row 20 = w1
    __shared__ float4 sS4[T*SP4];         //  5200 B (scores -> at in place)
    __shared__ float4 sHtilP[2][D4];      //   800 B
    __shared__ float4 sU1q4[2][5];        //   160 B (double-buffered U1)
    __shared__ float  sScal[T];           //   260 B: h1 -> beta (in place)

    const int tid  = threadIdx.x;
    const int wv   = tid >> 6;
    const int lane = tid & 63;
    const int b0   = blockIdx.x * NBPB;

    const float4* Hg4 = (const float4*)Hg;
    const float4* Ug4 = (const float4*)Ug;
    const float4* w3g = (const float4*)Ws3;   // row 0 (all rows identical)
    const float4* w2g = (const float4*)Ws2;
    float* sSf = (float*)sS4;

    // ================= Prologue: stage batch b0 =================
    {
        const float4* Hb0 = Hg4 + (size_t)b0 * 1625;
        for (int i = tid; i < T*D4; i += 256) sH4[i] = Hb0[i];
        const float4* Ub0 = Ug4 + (size_t)b0 * 500;
        for (int i = tid; i < Q*D4; i += 256) {
            const float4 u = Ub0[i];
            const int dd = i - (i/D4)*D4;
            const float4 w = w3g[dd];
            float4 v; v.x=u.x*w.x; v.y=u.y*w.y; v.z=u.z*w.z; v.w=u.w*w.w;
            sU3e4[i] = v;
        }
        if (tid < D4) sU3e4[Q*D4 + tid] = ((const float4*)Ws1)[tid];
        if (tid >= 192 && tid < 192 + Q) {
            const int q = tid - 192;
            const float4* ur = Ub0 + q*D4;
            float acc = 0.f;
            #pragma unroll 5
            for (int k = 0; k < D4; ++k) {
                const float4 u = ur[k], w = w2g[k];
                acc = fmaf(u.x, w.x, acc); acc = fmaf(u.y, w.y, acc);
                acc = fmaf(u.z, w.z, acc); acc = fmaf(u.w, w.w, acc);
            }
            ((float*)sU1q4[0])[q] = acc;
        }
    }
    __syncthreads();

    // ================= Main loop over NBPB batches =================
    #pragma unroll 1
    for (int j = 0; j < NBPB; ++j) {
        const int b    = b0 + j;
        const int cur  = j & 1;
        const int nxt  = cur ^ 1;
        const bool more = (j + 1 < NBPB);
        const float4* Ub = Ug4 + (size_t)b * 500;
        const float4* Hb = Hg4 + (size_t)b * 1625;
        const float4* Hn = Hg4 + (size_t)(b+1) * 1625;  // used only if more
        const float4* Un = Ug4 + (size_t)(b+1) * 500;
        float* Gb = Gg + (size_t)b * 26000;

        // ---- P3: S''[t,c] = H[t]·U3e[c] (4t x 3c, 119 lanes, waves 0-1) ----
        if (tid < 119) {
            const int tg = tid / 7;
            const int jg = tid - tg*7;
            int rb0 = ((tg*4 + 0) < T ? (tg*4 + 0) : T-1) * D4;
            int rb1 = ((tg*4 + 1) < T ? (tg*4 + 1) : T-1) * D4;
            int rb2 = ((tg*4 + 2) < T ? (tg*4 + 2) : T-1) * D4;
            int rb3 = ((tg*4 + 3) < T ? (tg*4 + 3) : T-1) * D4;
            float acc[4][3];
            #pragma unroll
            for (int i = 0; i < 4; ++i)
                #pragma unroll
                for (int k = 0; k < 3; ++k) acc[i][k] = 0.f;
            #pragma unroll 5
            for (int d4 = 0; d4 < D4; ++d4) {
                float4 h0 = sH4[rb0 + d4];
                float4 h1 = sH4[rb1 + d4];
                float4 h2 = sH4[rb2 + d4];
                float4 h3 = sH4[rb3 + d4];
                #pragma unroll
                for (int k = 0; k < 3; ++k) {
                    const float4 w = sU3e4[(jg*3+k)*D4 + d4];
                    acc[0][k] = fmaf(h0.x, w.x, acc[0][k]); acc[0][k] = fmaf(h0.y, w.y, acc[0][k]);
                    acc[0][k] = fmaf(h0.z, w.z, acc[0][k]); acc[0][k] = fmaf(h0.w, w.w, acc[0][k]);
                    acc[1][k] = fmaf(h1.x, w.x, acc[1][k]); acc[1][k] = fmaf(h1.y, w.y, acc[1][k]);
                    acc[1][k] = fmaf(h1.z, w.z, acc[1][k]); acc[1][k] = fmaf(h1.w, w.w, acc[1][k]);
                    acc[2][k] = fmaf(h2.x, w.x, acc[2][k]); acc[2][k] = fmaf(h2.y, w.y, acc[2][k]);
                    acc[2][k] = fmaf(h2.z, w.z, acc[2][k]); acc[2][k] = fmaf(h2.w, w.w, acc[2][k]);
                    acc[3][k] = fmaf(h3.x, w.x, acc[3][k]); acc[3][k] = fmaf(h3.y, w.y, acc[3][k]);
                    acc[3][k] = fmaf(h3.z, w.z, acc[3][k]); acc[3][k] = fmaf(h3.w, w.w, acc[3][k]);
                }
            }
            #pragma unroll
            for (int i = 0; i < 4; ++i) {
                const int t = tg*4 + i;
                if (t < T) {
                    #pragma unroll
                    for (int k = 0; k < 3; ++k) {
                        const int cc = jg*3 + k;
                        if (cc < Q) sSf[t*Q + cc] = acc[i][k];
                        else        sScal[t] = acc[i][k];     // h1[t]
                    }
                }
            }
        }
        __syncthreads();   // bar2

        // ---- P4: softmax-q (tid<65) ∥ waves 2-3 build U3e(b+1) ----
        if (tid < T) {
            const int t = tid;
            float4 r[SP4];
            #pragma unroll
            for (int c = 0; c < SP4; ++c) {
                r[c] = sS4[t*SP4 + c];
                const float4 u1 = sU1q4[cur][c];
                r[c].x += u1.x; r[c].y += u1.y; r[c].z += u1.z; r[c].w += u1.w;
            }
            float m = -1e30f;
            #pragma unroll
            for (int c = 0; c < SP4; ++c)
                m = fmaxf(m, fmaxf(fmaxf(r[c].x, r[c].y), fmaxf(r[c].z, r[c].w)));
            float s = 0.f;
            #pragma unroll
            for (int c = 0; c < SP4; ++c) {
                r[c].x = __expf(r[c].x - m); r[c].y = __expf(r[c].y - m);
                r[c].z = __expf(r[c].z - m); r[c].w = __expf(r[c].w - m);
                s += r[c].x + r[c].y + r[c].z + r[c].w;
            }
            const float inv = 1.f / s;
            #pragma unroll
            for (int c = 0; c < SP4; ++c) {
                r[c].x *= inv; r[c].y *= inv; r[c].z *= inv; r[c].w *= inv;
                sS4[t*SP4 + c] = r[c];
            }
            sScal[t] = sScal[t] + m;     // beta[t] (in place)
        } else if (more && tid >= 128) {
            for (int i = tid - 128; i < Q*D4; i += 128) {
                const float4 u = Un[i];
                const int dd = i - (i/D4)*D4;
                const float4 w = w3g[dd];
                float4 v; v.x=u.x*w.x; v.y=u.y*w.y; v.z=u.z*w.z; v.w=u.w*w.w;
                sU3e4[i] = v;
            }
        }
        __syncthreads();   // bar3

        // ---- P5+P6 fused (waves 0-1) ∥ wave 2 lanes 0-19: U1(b+1) ----
        if (wv < 2) {
            const float v0 = sScal[lane];
            const float v1 = (lane == 0) ? sScal[64] : -1e30f;
            float mx = fmaxf(v0, v1);
            #pragma unroll
            for (int off = 32; off >= 1; off >>= 1)
                mx = fmaxf(mx, __shfl_xor(mx, off, 64));
            const float e0 = __expf(v0 - mx);
            const float e1 = (lane == 0) ? __expf(v1 - mx) : 0.f;
            float s = e0 + e1;
            #pragma unroll
            for (int off = 32; off >= 1; off >>= 1)
                s += __shfl_xor(s, off, 64);
            const float inv = 1.f / s;
            if (lane < D4) {
                float4 acc = {0.f, 0.f, 0.f, 0.f};
                for (int t = wv; t < T; t += 2) {
                    const float bt = __expf(sScal[t] - mx) * inv;
                    const float4 h = sH4[t*D4 + lane];
                    acc.x = fmaf(bt, h.x, acc.x); acc.y = fmaf(bt, h.y, acc.y);
                    acc.z = fmaf(bt, h.z, acc.z); acc.w = fmaf(bt, h.w, acc.w);
                }
                sHtilP[wv][lane] = acc;
            }
        } else if (more && wv == 2 && lane < Q) {
            const float4* ur = Un + lane*D4;              // L2-warm (just read in P4 window)
            float acc = 0.f;
            #pragma unroll 5
            for (int k = 0; k < D4; ++k) {
                const float4 u = ur[k], w = w2g[k];
                acc = fmaf(u.x, w.x, acc); acc = fmaf(u.y, w.y, acc);
                acc = fmaf(u.z, w.z, acc); acc = fmaf(u.w, w.w, acc);
            }
            ((float*)sU1q4[nxt])[lane] = acc;
        }
        __syncthreads();   // bar4  (sH4 now dead until refilled)

        // ---- P7: issue async H(b+1)->sH4 prefetch, then store burst.
        //      hv comes from GLOBAL (L2-warm, 400B-contiguous per 25 lanes). ----
        if (more) {
            #pragma unroll 1
            for (int i = wv; i < 25; i += 4) {    // chunks 0..24 = elements 0..1599
                __builtin_amdgcn_global_load_lds(
                    (const __attribute__((address_space(1))) void*)(Hn + i*64 + lane),
                    (__attribute__((address_space(3))) void*)(sH4 + i*64), 16, 0, 0);
            }
        }
        {
            const int tsel = (lane < 50) ? (lane / 25) : 0;
            const int g    = (lane < 50) ? (lane - tsel*25) : (lane - 50);
            const bool act = (lane < 50);

            // tail elements 1600..1624 on idle lanes of waves 0-1
            if (more && lane >= 50) {
                const int tl = wv*14 + (lane - 50);
                if (tl < 25) sH4[1600 + tl] = Hn[1600 + tl];
            }

            const float4 p0 = sHtilP[0][g], p1 = sHtilP[1][g];
            float4 htil;
            htil.x = p0.x+p1.x; htil.y = p0.y+p1.y;
            htil.z = p0.z+p1.z; htil.w = p0.w+p1.w;

            float4 u[Q];                       // 80 VGPRs (global, L2-warm)
            #pragma unroll
            for (int q = 0; q < Q; ++q) u[q] = Ub[q*D4 + g];

            #pragma unroll 1
            for (int pr = wv; pr < 33; pr += 4) {
                const int t   = pr*2 + tsel;
                const bool val = act && (t < T);
                const int tr  = val ? t : 0;

                float4 acc = {0.f, 0.f, 0.f, 0.f};
                #define QSTEP(av, comp, qq) { \
                    acc.x = fmaf(av.comp, u[qq].x, acc.x); \
                    acc.y = fmaf(av.comp, u[qq].y, acc.y); \
                    acc.z = fmaf(av.comp, u[qq].z, acc.z); \
                    acc.w = fmaf(av.comp, u[qq].w, acc.w); }
                {
                    float4 a = sS4[tr*SP4 + 0];
                    QSTEP(a,x,0)  QSTEP(a,y,1)  QSTEP(a,z,2)  QSTEP(a,w,3)
                    a = sS4[tr*SP4 + 1];
                    QSTEP(a,x,4)  QSTEP(a,y,5)  QSTEP(a,z,6)  QSTEP(a,w,7)
                    a = sS4[tr*SP4 + 2];
                    QSTEP(a,x,8)  QSTEP(a,y,9)  QSTEP(a,z,10) QSTEP(a,w,11)
                    a = sS4[tr*SP4 + 3];
                    QSTEP(a,x,12) QSTEP(a,y,13) QSTEP(a,z,14) QSTEP(a,w,15)
                    a = sS4[tr*SP4 + 4];
                    QSTEP(a,x,16) QSTEP(a,y,17) QSTEP(a,z,18) QSTEP(a,w,19)
                }
                #undef QSTEP

                const float4 hv = Hb[tr*D4 + g];      // GLOBAL, L2-warm
                if (val) {
                    float4 hu, hh;
                    hu.x = hv.x*acc.x;  hu.y = hv.y*acc.y;  hu.z = hv.z*acc.z;  hu.w = hv.w*acc.w;
                    hh.x = hv.x*htil.x; hh.y = hv.y*htil.y; hh.z = hv.z*htil.z; hh.w = hv.w*htil.w;
                    float4* base = (float4*)(Gb + (size_t)t*(4*D));
                    base[g]        = hv;      // segment 1: H
                    base[D4 + g]   = acc;     // segment 2: Util
                    base[2*D4 + g] = hu;      // segment 3: H*Util
                    base[3*D4 + g] = hh;      // segment 4: H*Htil
                }
            }
        }
        __syncthreads();   // bar-end: drains prefetch (+ store tail)
    }
}

extern "C" void kernel_launch(void* const* d_in, const int* in_sizes, int n_in,
                              void* d_out, int out_size, void* d_ws, size_t ws_size,
                              hipStream_t stream) {
    const float* H   = (const float*)d_in[0];
    const float* U   = (const float*)d_in[1];
    const float* Ws1 = (const float*)d_in[2];
    const float* Ws2 = (const float*)d_in[3];
    const float* Ws3 = (const float*)d_in[4];
    float* G = (float*)d_out;
    hipLaunchKernelGGL(attn_fused_kernel, dim3(NB / NBPB), dim3(256), 0, stream,
                       H, U, Ws1, Ws2, Ws3, G);
}

// Round 13
// 271.301 us; speedup vs baseline: 1.4480x; 1.4480x over previous
//
#include <hip/hip_runtime.h>
#include <math.h>

#define NB 8192
#define T 65
#define Q 20
#define D 100
#define D4 25        // D/4
#define SP4 5        // sS row pitch in float4 (= Q floats exactly)

__global__ __launch_bounds__(256, 4) void attn_fused_kernel(
    const float* __restrict__ Hg,   // [B,T,D]
    const float* __restrict__ Ug,   // [B,Q,D]
    const float* __restrict__ Ws1,  // [T,D] (tiled single row)
    const float* __restrict__ Ws2,  // [Q,D]
    const float* __restrict__ Ws3,  // [T,D]
    float* __restrict__ Gg)         // [B,T,4D]
{
    // 26000 + 8400 + 5200 + 80 + 260 = 39940 B -> 4 blocks/CU
    __shared__ float4 sH4[T*D4];          // 26000 B
    __shared__ float4 sU3e4[(Q+1)*D4];    //  8400 B: rows 0..19 = U*w3, row 20 = w1
    __shared__ float4 sS4[T*SP4];         //  5200 B (scores -> at in place)
    __shared__ float4 sU1q4[5];           //    80 B
    __shared__ float  sScal[T];           //   260 B: h1 -> beta (in place)

    const int tid  = threadIdx.x;
    const int wv   = tid >> 6;
    const int lane = tid & 63;
    const int b    = blockIdx.x;

    // P7 lane geometry (also used for u-hoist and htil)
    const int tsel = (lane < 50) ? (lane / 25) : 0;   // half: 0 = even t, 1 = odd t
    const int g    = (lane < 50) ? (lane - tsel*25) : (lane - 50);
    const bool act = (lane < 50);

    const float4* Hb = (const float4*)(Hg + (size_t)b * (T*D));
    const float4* Ub = (const float4*)(Ug + (size_t)b * (Q*D));
    float* Gb = Gg + (size_t)b * (T*4*D);
    float* sSf = (float*)sS4;

    // ---- P1: stage H; build U*w3 from in-flight regs; w1 row ----
    {
        const float4* w3g = (const float4*)Ws3;   // row 0 (all rows identical)
        for (int i = tid; i < T*D4; i += 256) sH4[i] = Hb[i];
        for (int i = tid; i < Q*D4; i += 256) {
            const float4 u = Ub[i];
            const int dd = i - (i/D4)*D4;
            const float4 w = w3g[dd];
            float4 v; v.x=u.x*w.x; v.y=u.y*w.y; v.z=u.z*w.z; v.w=u.w*w.w;
            sU3e4[i] = v;
        }
        if (tid < D4) sU3e4[Q*D4 + tid] = ((const float4*)Ws1)[tid];
    }
    __syncthreads();   // bar1

    // ---- P3: S''[t,c] = H[t]·U3e[c] (65x21 GEMM; 4t x 3c, 119 lanes, waves 0-1)
    //      wave 2 (tid 128..147) concurrently: U1[q] = U[q]·w2 from GLOBAL (L2-warm)
    if (tid < 119) {
        const int tg = tid / 7;          // 0..16
        const int jg = tid - tg*7;       // 0..6
        int rb0 = ((tg*4 + 0) < T ? (tg*4 + 0) : T-1) * D4;
        int rb1 = ((tg*4 + 1) < T ? (tg*4 + 1) : T-1) * D4;
        int rb2 = ((tg*4 + 2) < T ? (tg*4 + 2) : T-1) * D4;
        int rb3 = ((tg*4 + 3) < T ? (tg*4 + 3) : T-1) * D4;
        float acc[4][3];
        #pragma unroll
        for (int i = 0; i < 4; ++i)
            #pragma unroll
            for (int k = 0; k < 3; ++k) acc[i][k] = 0.f;
        #pragma unroll 5
        for (int d4 = 0; d4 < D4; ++d4) {
            float4 h0 = sH4[rb0 + d4];
            float4 h1 = sH4[rb1 + d4];
            float4 h2 = sH4[rb2 + d4];
            float4 h3 = sH4[rb3 + d4];
            #pragma unroll
            for (int k = 0; k < 3; ++k) {
                const float4 w = sU3e4[(jg*3+k)*D4 + d4];
                acc[0][k] = fmaf(h0.x, w.x, acc[0][k]); acc[0][k] = fmaf(h0.y, w.y, acc[0][k]);
                acc[0][k] = fmaf(h0.z, w.z, acc[0][k]); acc[0][k] = fmaf(h0.w, w.w, acc[0][k]);
                acc[1][k] = fmaf(h1.x, w.x, acc[1][k]); acc[1][k] = fmaf(h1.y, w.y, acc[1][k]);
                acc[1][k] = fmaf(h1.z, w.z, acc[1][k]); acc[1][k] = fmaf(h1.w, w.w, acc[1][k]);
                acc[2][k] = fmaf(h2.x, w.x, acc[2][k]); acc[2][k] = fmaf(h2.y, w.y, acc[2][k]);
                acc[2][k] = fmaf(h2.z, w.z, acc[2][k]); acc[2][k] = fmaf(h2.w, w.w, acc[2][k]);
                acc[3][k] = fmaf(h3.x, w.x, acc[3][k]); acc[3][k] = fmaf(h3.y, w.y, acc[3][k]);
                acc[3][k] = fmaf(h3.z, w.z, acc[3][k]); acc[3][k] = fmaf(h3.w, w.w, acc[3][k]);
            }
        }
        #pragma unroll
        for (int i = 0; i < 4; ++i) {
            const int t = tg*4 + i;
            if (t < T) {
                #pragma unroll
                for (int k = 0; k < 3; ++k) {
                    const int cc = jg*3 + k;
                    if (cc < Q) sSf[t*Q + cc] = acc[i][k];
                    else        sScal[t] = acc[i][k];     // cc == 20: h1[t]
                }
            }
        }
    } else if (tid >= 128 && tid < 128 + Q) {
        const int q = tid - 128;
        const float4* ur = Ub + q*D4;                     // global, L2-warm
        const float4* w2 = (const float4*)Ws2;
        float acc = 0.f;
        #pragma unroll 5
        for (int k = 0; k < D4; ++k) {
            const float4 u = ur[k], w = w2[k];
            acc = fmaf(u.x, w.x, acc); acc = fmaf(u.y, w.y, acc);
            acc = fmaf(u.z, w.z, acc); acc = fmaf(u.w, w.w, acc);
        }
        ((float*)sU1q4)[q] = acc;
    }
    __syncthreads();   // bar2

    // ---- P4: add U1, softmax over q (in place), beta[t] = h1[t] + max ----
    if (tid < T) {
        const int t = tid;
        float4 r[SP4];
        #pragma unroll
        for (int c = 0; c < SP4; ++c) {
            r[c] = sS4[t*SP4 + c];
            const float4 u1 = sU1q4[c];
            r[c].x += u1.x; r[c].y += u1.y; r[c].z += u1.z; r[c].w += u1.w;
        }
        float m = -1e30f;
        #pragma unroll
        for (int c = 0; c < SP4; ++c)
            m = fmaxf(m, fmaxf(fmaxf(r[c].x, r[c].y), fmaxf(r[c].z, r[c].w)));
        float s = 0.f;
        #pragma unroll
        for (int c = 0; c < SP4; ++c) {
            r[c].x = __expf(r[c].x - m); r[c].y = __expf(r[c].y - m);
            r[c].z = __expf(r[c].z - m); r[c].w = __expf(r[c].w - m);
            s += r[c].x + r[c].y + r[c].z + r[c].w;
        }
        const float inv = 1.f / s;
        #pragma unroll
        for (int c = 0; c < SP4; ++c) {
            r[c].x *= inv; r[c].y *= inv; r[c].z *= inv; r[c].w *= inv;
            sS4[t*SP4 + c] = r[c];
        }
        sScal[t] = sScal[t] + m;     // beta[t] = h1[t] + m (in place)
    }
    __syncthreads();   // bar3  (LAST barrier)

    // ========== Mega-phase (no further barriers): P5+P6 in-register, then P7 ==========
    {
        // u-hoist issued first: L2 latency hides under the reduce + htil loop
        float4 u[Q];                       // 80 VGPRs, static-indexed (global, L2-warm)
        #pragma unroll
        for (int q = 0; q < Q; ++q) u[q] = Ub[q*D4 + g];

        // per-wave redundant beta softmax reduce (all 64 lanes)
        const float v0 = sScal[lane];
        const float v1 = (lane == 0) ? sScal[64] : -1e30f;
        float mx = fmaxf(v0, v1);
        #pragma unroll
        for (int off = 32; off >= 1; off >>= 1)
            mx = fmaxf(mx, __shfl_xor(mx, off, 64));
        const float e0 = __expf(v0 - mx);
        const float e1 = (lane == 0) ? __expf(v1 - mx) : 0.f;
        float s = e0 + e1;
        #pragma unroll
        for (int off = 32; off >= 1; off >>= 1)
            s += __shfl_xor(s, off, 64);
        const float inv = 1.f / s;

        // htil in registers: lanes 0..49; half tsel accumulates its t-parity
        float4 htil = {0.f, 0.f, 0.f, 0.f};
        if (act) {
            #pragma unroll 4
            for (int tt = tsel; tt < T; tt += 2) {
                const float bt = __expf(sScal[tt] - mx) * inv;
                const float4 h = sH4[tt*D4 + g];
                htil.x = fmaf(bt, h.x, htil.x); htil.y = fmaf(bt, h.y, htil.y);
                htil.z = fmaf(bt, h.z, htil.z); htil.w = fmaf(bt, h.w, htil.w);
            }
        }
        // merge even/odd halves across the 25-lane groups
        {
            const int partner = act ? ((lane < 25) ? lane + 25 : lane - 25) : lane;
            htil.x += __shfl(htil.x, partner, 64);
            htil.y += __shfl(htil.y, partner, 64);
            htil.z += __shfl(htil.z, partner, 64);
            htil.w += __shfl(htil.w, partner, 64);
        }

        // ---- P7: output, 2t x 25g lanes per pair; staggered at-row loads ----
        #pragma unroll 1
        for (int pr = wv; pr < 33; pr += 4) {
            const int t   = pr*2 + tsel;
            const bool val = act && (t < T);
            const int tr  = val ? t : 0;

            float4 acc = {0.f, 0.f, 0.f, 0.f};
            #define QSTEP(av, comp, qq) { \
                acc.x = fmaf(av.comp, u[qq].x, acc.x); \
                acc.y = fmaf(av.comp, u[qq].y, acc.y); \
                acc.z = fmaf(av.comp, u[qq].z, acc.z); \
                acc.w = fmaf(av.comp, u[qq].w, acc.w); }
            {
                float4 a = sS4[tr*SP4 + 0];
                QSTEP(a,x,0)  QSTEP(a,y,1)  QSTEP(a,z,2)  QSTEP(a,w,3)
                a = sS4[tr*SP4 + 1];
                QSTEP(a,x,4)  QSTEP(a,y,5)  QSTEP(a,z,6)  QSTEP(a,w,7)
                a = sS4[tr*SP4 + 2];
                QSTEP(a,x,8)  QSTEP(a,y,9)  QSTEP(a,z,10) QSTEP(a,w,11)
                a = sS4[tr*SP4 + 3];
                QSTEP(a,x,12) QSTEP(a,y,13) QSTEP(a,z,14) QSTEP(a,w,15)
                a = sS4[tr*SP4 + 4];
                QSTEP(a,x,16) QSTEP(a,y,17) QSTEP(a,z,18) QSTEP(a,w,19)
            }
            #undef QSTEP

            const float4 hv = sH4[tr*D4 + g];
            if (val) {
                float4 hu, hh;
                hu.x = hv.x*acc.x;  hu.y = hv.y*acc.y;  hu.z = hv.z*acc.z;  hu.w = hv.w*acc.w;
                hh.x = hv.x*htil.x; hh.y = hv.y*htil.y; hh.z = hv.z*htil.z; hh.w = hv.w*htil.w;
                float4* base = (float4*)(Gb + (size_t)t*(4*D));
                base[g]        = hv;      // segment 1: H
                base[D4 + g]   = acc;     // segment 2: Util
                base[2*D4 + g] = hu;      // segment 3: H*Util
                base[3*D4 + g] = hh;      // segment 4: H*Htil
            }
        }
    }
}

extern "C" void kernel_launch(void* const* d_in, const int* in_sizes, int n_in,
                              void* d_out, int out_size, void* d_ws, size_t ws_size,
                              hipStream_t stream) {
    const float* H   = (const float*)d_in[0];
    const float* U   = (const float*)d_in[1];
    const float* Ws1 = (const float*)d_in[2];
    const float* Ws2 = (const float*)d_in[3];
    const float* Ws3 = (const float*)d_in[4];
    float* G = (float*)d_out;
    hipLaunchKernelGGL(attn_fused_kernel, dim3(NB), dim3(256), 0, stream,
                       H, U, Ws1, Ws2, Ws3, G);
}

// Round 14
// 268.092 us; speedup vs baseline: 1.4654x; 1.0120x over previous
//
#include <hip/hip_runtime.h>
#include <math.h>

#define NB 8192
#define T 65
#define Q 20
#define D 100
#define D4 25        // D/4
#define SP4 5        // sS row pitch in float4 (= Q floats exactly)

__global__ __launch_bounds__(256, 4) void attn_fused_kernel(
    const float* __restrict__ Hg,   // [B,T,D]
    const float* __restrict__ Ug,   // [B,Q,D]
    const float* __restrict__ Ws1,  // [T,D] (tiled single row)
    const float* __restrict__ Ws2,  // [Q,D]
    const float* __restrict__ Ws3,  // [T,D]
    float* __restrict__ Gg)         // [B,T,4D]
{
    // 26000 + 8400 + 5200 + 800 + 80 + 260 = 40740 B -> 4 blocks/CU (160 KiB)
    __shared__ float4 sH4[T*D4];          // 26000 B
    __shared__ float4 sU3e4[(Q+1)*D4];    //  8400 B: rows 0..19 = U*w3, row 20 = w1
    __shared__ float4 sS4[T*SP4];         //  5200 B (scores -> at in place)
    __shared__ float4 sHtilP[2][D4];      //   800 B (waves 0-1 partials)
    __shared__ float4 sU1q4[5];           //    80 B
    __shared__ float  sScal[T];           //   260 B: h1 -> beta -> bsm (in place)

    const int b    = blockIdx.x;
    const int tid  = threadIdx.x;
    const int wv   = tid >> 6;
    const int lane = tid & 63;
    const float4* Hb = (const float4*)(Hg + (size_t)b * (T*D));
    const float4* Ub = (const float4*)(Ug + (size_t)b * (Q*D));
    float* Gb = Gg + (size_t)b * (T*4*D);
    float* sSf = (float*)sS4;

    // ---- P1: stage H; build U*w3 from in-flight regs; w1 row ----
    for (int i = tid; i < T*D4; i += 256) sH4[i] = Hb[i];
    {
        const float4* w3g = (const float4*)Ws3;   // row 0 (all rows identical)
        for (int i = tid; i < Q*D4; i += 256) {
            const float4 u = Ub[i];
            const int dd = i - (i/D4)*D4;
            const float4 w = w3g[dd];
            float4 v; v.x=u.x*w.x; v.y=u.y*w.y; v.z=u.z*w.z; v.w=u.w*w.w;
            sU3e4[i] = v;
        }
        if (tid < D4) sU3e4[Q*D4 + tid] = ((const float4*)Ws1)[tid];
    }
    __syncthreads();   // bar1

    // ---- P3: S''[t,c] = H[t]·U3e[c] (65x21 GEMM; 4t x 3c, 119 lanes, waves 0-1)
    //      wave 2 (tid 128..147) concurrently: U1[q] = U[q]·w2 from GLOBAL (L2-warm)
    if (tid < 119) {
        const int tg = tid / 7;          // 0..16
        const int jg = tid - tg*7;       // 0..6
        int rb0 = ((tg*4 + 0) < T ? (tg*4 + 0) : T-1) * D4;
        int rb1 = ((tg*4 + 1) < T ? (tg*4 + 1) : T-1) * D4;
        int rb2 = ((tg*4 + 2) < T ? (tg*4 + 2) : T-1) * D4;
        int rb3 = ((tg*4 + 3) < T ? (tg*4 + 3) : T-1) * D4;
        float acc[4][3];
        #pragma unroll
        for (int i = 0; i < 4; ++i)
            #pragma unroll
            for (int k = 0; k < 3; ++k) acc[i][k] = 0.f;
        #pragma unroll 5
        for (int d4 = 0; d4 < D4; ++d4) {
            float4 h0 = sH4[rb0 + d4];
            float4 h1 = sH4[rb1 + d4];
            float4 h2 = sH4[rb2 + d4];
            float4 h3 = sH4[rb3 + d4];
            #pragma unroll
            for (int k = 0; k < 3; ++k) {
                const float4 w = sU3e4[(jg*3+k)*D4 + d4];
                acc[0][k] = fmaf(h0.x, w.x, acc[0][k]); acc[0][k] = fmaf(h0.y, w.y, acc[0][k]);
                acc[0][k] = fmaf(h0.z, w.z, acc[0][k]); acc[0][k] = fmaf(h0.w, w.w, acc[0][k]);
                acc[1][k] = fmaf(h1.x, w.x, acc[1][k]); acc[1][k] = fmaf(h1.y, w.y, acc[1][k]);
                acc[1][k] = fmaf(h1.z, w.z, acc[1][k]); acc[1][k] = fmaf(h1.w, w.w, acc[1][k]);
                acc[2][k] = fmaf(h2.x, w.x, acc[2][k]); acc[2][k] = fmaf(h2.y, w.y, acc[2][k]);
                acc[2][k] = fmaf(h2.z, w.z, acc[2][k]); acc[2][k] = fmaf(h2.w, w.w, acc[2][k]);
                acc[3][k] = fmaf(h3.x, w.x, acc[3][k]); acc[3][k] = fmaf(h3.y, w.y, acc[3][k]);
                acc[3][k] = fmaf(h3.z, w.z, acc[3][k]); acc[3][k] = fmaf(h3.w, w.w, acc[3][k]);
            }
        }
        #pragma unroll
        for (int i = 0; i < 4; ++i) {
            const int t = tg*4 + i;
            if (t < T) {
                #pragma unroll
                for (int k = 0; k < 3; ++k) {
                    const int cc = jg*3 + k;
                    if (cc < Q) sSf[t*Q + cc] = acc[i][k];
                    else        sScal[t] = acc[i][k];     // cc == 20: h1[t]
                }
            }
        }
    } else if (tid >= 128 && tid < 128 + Q) {
        const int q = tid - 128;
        const float4* ur = Ub + q*D4;                     // global, L2-warm
        const float4* w2 = (const float4*)Ws2;
        float acc = 0.f;
        #pragma unroll 5
        for (int k = 0; k < D4; ++k) {
            const float4 u = ur[k], w = w2[k];
            acc = fmaf(u.x, w.x, acc); acc = fmaf(u.y, w.y, acc);
            acc = fmaf(u.z, w.z, acc); acc = fmaf(u.w, w.w, acc);
        }
        ((float*)sU1q4)[q] = acc;
    }
    __syncthreads();   // bar2

    // ---- P4: add U1, softmax over q (in place), beta[t] = h1[t] + max ----
    if (tid < T) {
        const int t = tid;
        float4 r[SP4];
        #pragma unroll
        for (int c = 0; c < SP4; ++c) {
            r[c] = sS4[t*SP4 + c];
            const float4 u1 = sU1q4[c];
            r[c].x += u1.x; r[c].y += u1.y; r[c].z += u1.z; r[c].w += u1.w;
        }
        float m = -1e30f;
        #pragma unroll
        for (int c = 0; c < SP4; ++c)
            m = fmaxf(m, fmaxf(fmaxf(r[c].x, r[c].y), fmaxf(r[c].z, r[c].w)));
        float s = 0.f;
        #pragma unroll
        for (int c = 0; c < SP4; ++c) {
            r[c].x = __expf(r[c].x - m); r[c].y = __expf(r[c].y - m);
            r[c].z = __expf(r[c].z - m); r[c].w = __expf(r[c].w - m);
            s += r[c].x + r[c].y + r[c].z + r[c].w;
        }
        const float inv = 1.f / s;
        #pragma unroll
        for (int c = 0; c < SP4; ++c) {
            r[c].x *= inv; r[c].y *= inv; r[c].z *= inv; r[c].w *= inv;
            sS4[t*SP4 + c] = r[c];
        }
        sScal[t] = sScal[t] + m;     // beta[t] = h1[t] + m (in place)
    }
    __syncthreads();   // bar3

    // ---- P5: softmax over t of beta (wave 0; lane 0 also owns t=64), in place ----
    if (tid < 64) {
        const float v0 = sScal[tid];
        const float v1 = (tid == 0) ? sScal[64] : -1e30f;
        float mx = fmaxf(v0, v1);
        #pragma unroll
        for (int off = 32; off >= 1; off >>= 1)
            mx = fmaxf(mx, __shfl_xor(mx, off, 64));
        const float e0 = __expf(v0 - mx);
        const float e1 = (tid == 0) ? __expf(v1 - mx) : 0.f;
        float s = e0 + e1;
        #pragma unroll
        for (int off = 32; off >= 1; off >>= 1)
            s += __shfl_xor(s, off, 64);
        const float inv = 1.f / s;
        sScal[tid] = e0 * inv;
        if (tid == 0) sScal[64] = e1 * inv;
    }
    __syncthreads();   // bar4

    // ---- P6: Htil partials on waves 0-1 (even/odd t), from sH4 ----
    if (wv < 2 && lane < D4) {
        float4 acc = {0.f, 0.f, 0.f, 0.f};
        for (int t = wv; t < T; t += 2) {
            const float bt = sScal[t];
            const float4 h = sH4[t*D4 + lane];
            acc.x = fmaf(bt, h.x, acc.x); acc.y = fmaf(bt, h.y, acc.y);
            acc.z = fmaf(bt, h.z, acc.z); acc.w = fmaf(bt, h.w, acc.w);
        }
        sHtilP[wv][lane] = acc;
    }
    __syncthreads();   // bar5

    // ---- P7: output. 2t x 25g lanes per pair; U hoisted to regs from GLOBAL;
    //          at-rows loaded STAGGERED (one float4 live at a time) ----
    {
        const int tsel = (lane < 50) ? (lane / 25) : 0;
        const int g    = (lane < 50) ? (lane - tsel*25) : (lane - 50);
        const bool act = (lane < 50);

        const float4 p0 = sHtilP[0][g], p1 = sHtilP[1][g];
        float4 htil;
        htil.x = p0.x+p1.x; htil.y = p0.y+p1.y;
        htil.z = p0.z+p1.z; htil.w = p0.w+p1.w;

        float4 u[Q];                       // 80 VGPRs, static-indexed (global, L2-warm)
        #pragma unroll
        for (int q = 0; q < Q; ++q) u[q] = Ub[q*D4 + g];

        #pragma unroll 1
        for (int pr = wv; pr < 33; pr += 4) {
            const int t   = pr*2 + tsel;
            const bool val = act && (t < T);
            const int tr  = val ? t : 0;

            float4 acc = {0.f, 0.f, 0.f, 0.f};
            #define QSTEP(av, comp, qq) { \
                acc.x = fmaf(av.comp, u[qq].x, acc.x); \
                acc.y = fmaf(av.comp, u[qq].y, acc.y); \
                acc.z = fmaf(av.comp, u[qq].z, acc.z); \
                acc.w = fmaf(av.comp, u[qq].w, acc.w); }
            {
                float4 a = sS4[tr*SP4 + 0];
                QSTEP(a,x,0)  QSTEP(a,y,1)  QSTEP(a,z,2)  QSTEP(a,w,3)
                a = sS4[tr*SP4 + 1];
                QSTEP(a,x,4)  QSTEP(a,y,5)  QSTEP(a,z,6)  QSTEP(a,w,7)
                a = sS4[tr*SP4 + 2];
                QSTEP(a,x,8)  QSTEP(a,y,9)  QSTEP(a,z,10) QSTEP(a,w,11)
                a = sS4[tr*SP4 + 3];
                QSTEP(a,x,12) QSTEP(a,y,13) QSTEP(a,z,14) QSTEP(a,w,15)
                a = sS4[tr*SP4 + 4];
                QSTEP(a,x,16) QSTEP(a,y,17) QSTEP(a,z,18) QSTEP(a,w,19)
            }
            #undef QSTEP

            const float4 hv = sH4[tr*D4 + g];
            if (val) {
                float4 hu, hh;
                hu.x = hv.x*acc.x;  hu.y = hv.y*acc.y;  hu.z = hv.z*acc.z;  hu.w = hv.w*acc.w;
                hh.x = hv.x*htil.x; hh.y = hv.y*htil.y; hh.z = hv.z*htil.z; hh.w = hv.w*htil.w;
                float4* base = (float4*)(Gb + (size_t)t*(4*D));
                base[g]        = hv;
                base[D4 + g]   = acc;
                base[2*D4 + g] = hu;
                base[3*D4 + g] = hh;
            }
        }
    }
}

extern "C" void kernel_launch(void* const* d_in, const int* in_sizes, int n_in,
                              void* d_out, int out_size, void* d_ws, size_t ws_size,
                              hipStream_t stream) {
    const float* H   = (const float*)d_in[0];
    const float* U   = (const float*)d_in[1];
    const float* Ws1 = (const float*)d_in[2];
    const float* Ws2 = (const float*)d_in[3];
    const float* Ws3 = (const float*)d_in[4];
    float* G = (float*)d_out;
    hipLaunchKernelGGL(attn_fused_kernel, dim3(NB), dim3(256), 0, stream,
                       H, U, Ws1, Ws2, Ws3, G);
}